// Round 2
// baseline (291.743 us; speedup 1.0000x reference)
//
#include <hip/hip_runtime.h>

// LIF recurrence over T, parallel over (B,H).
// x: (B,T,H) fp32; out: spikes (B,T,H) fp32.
// B=64, T=1000, H=512 (fixed by the problem).

#define LIF_B 64
#define LIF_T 1000
#define LIF_H 512
#define LIF_U 8   // chunk size; pipeline depth = 2 chunks (16 loads in flight)

__global__ __launch_bounds__(64) void lif_kernel(
    const float* __restrict__ x,
    const float* __restrict__ decay,
    const float* __restrict__ thr_p,
    float* __restrict__ out)
{
    const int n = blockIdx.x * blockDim.x + threadIdx.x;   // 0..32767
    const int b = n >> 9;        // / H
    const int h = n & (LIF_H - 1);

    // clamp(0.5, v, 1.0)
    const float alpha = fminf(fmaxf(decay[0], 0.5f), 1.0f);
    const float beta  = fminf(fmaxf(decay[1], 0.5f), 1.0f);
    // match XLA's separate-op rounding; no fma contraction anywhere
    const float oma = __fsub_rn(1.0f, alpha);
    const float omb = __fsub_rn(1.0f, beta);
    const float thr = thr_p[0];

    const size_t base = (size_t)b * LIF_T * LIF_H + h;
    const float* xp = x + base;
    float* op = out + base;

    float mem = 0.0f, syn = 0.0f, spike = 0.0f;

    float b0[LIF_U], b1[LIF_U], b2[LIF_U];
    #pragma unroll
    for (int u = 0; u < LIF_U; ++u) b0[u] = xp[(size_t)u * LIF_H];
    #pragma unroll
    for (int u = 0; u < LIF_U; ++u) b1[u] = xp[(size_t)(LIF_U + u) * LIF_H];

    for (int t = 0; t < LIF_T; t += LIF_U) {
        const int tp = t + 2 * LIF_U;
        if (tp < LIF_T) {
            #pragma unroll
            for (int u = 0; u < LIF_U; ++u)
                b2[u] = xp[(size_t)(tp + u) * LIF_H];
        }
        #pragma unroll
        for (int u = 0; u < LIF_U; ++u) {
            const float xv = b0[u];
            // reset_pot = mem * spike; mem -= reset_pot (exact: spike is 0/1)
            const float reset = __fmul_rn(mem, spike);
            mem = __fsub_rn(mem, reset);
            // mem = alpha*mem + (1-alpha)*syn   (separate rn ops, no fma)
            mem = __fadd_rn(__fmul_rn(alpha, mem), __fmul_rn(oma, syn));
            // syn = beta*syn + (1-beta)*x_t
            syn = __fadd_rn(__fmul_rn(beta, syn), __fmul_rn(omb, xv));
            // spike = heaviside(mem - thr, 1.0) -> (mem - thr >= 0) ? 1 : 0
            spike = (__fsub_rn(mem, thr) >= 0.0f) ? 1.0f : 0.0f;
            op[(size_t)(t + u) * LIF_H] = spike;
        }
        #pragma unroll
        for (int u = 0; u < LIF_U; ++u) { b0[u] = b1[u]; b1[u] = b2[u]; }
    }
}

extern "C" void kernel_launch(void* const* d_in, const int* in_sizes, int n_in,
                              void* d_out, int out_size, void* d_ws, size_t ws_size,
                              hipStream_t stream) {
    const float* x     = (const float*)d_in[0];
    const float* decay = (const float*)d_in[1];
    const float* thr   = (const float*)d_in[2];
    float* out = (float*)d_out;

    const int total = LIF_B * LIF_H;           // 32768 threads
    const int block = 64;
    const int grid  = total / block;           // 512 blocks -> 2 waves/CU
    lif_kernel<<<grid, block, 0, stream>>>(x, decay, thr, out);
}

// Round 3
// 245.913 us; speedup vs baseline: 1.1864x; 1.1864x over previous
//
#include <hip/hip_runtime.h>

// LIF recurrence over T, parallel over (B,H). x,out: (B,T,H) fp32.
// B=64, T=1000, H=512. 32768 threads = 512 waves (2/CU) -> latency hiding
// must come from ILP: ping-pong register buffers, U=20 loads in flight
// while the other chunk computes. No branches in the steady-state loop.

#define LIF_B 64
#define LIF_T 1000
#define LIF_H 512
#define LIF_U 20   // 1000 = 25 chunks of 40 = 2*U per iteration

__global__ __launch_bounds__(64) void lif_kernel(
    const float* __restrict__ x,
    const float* __restrict__ decay,
    const float* __restrict__ thr_p,
    float* __restrict__ out)
{
    const int n = blockIdx.x * 64 + threadIdx.x;   // 0..32767
    const int b = n >> 9;          // / H
    const int h = n & (LIF_H - 1);

    // clamp(0.5, v, 1.0)
    const float alpha = fminf(fmaxf(decay[0], 0.5f), 1.0f);
    const float beta  = fminf(fmaxf(decay[1], 0.5f), 1.0f);
    // match XLA's separate-op rounding; no fma contraction anywhere
    const float oma = __fsub_rn(1.0f, alpha);
    const float omb = __fsub_rn(1.0f, beta);
    const float thr = thr_p[0];

    const size_t base = (size_t)b * LIF_T * LIF_H + h;
    const float* xp = x + base;
    float* op = out + base;

    float mem = 0.0f, syn = 0.0f, spike = 0.0f;

// one LIF timestep consuming xv, storing spike at time tt
#define LIF_STEP(xv, tt) do {                                              \
        const float reset_ = __fmul_rn(mem, spike);                        \
        mem = __fsub_rn(mem, reset_);                                      \
        mem = __fadd_rn(__fmul_rn(alpha, mem), __fmul_rn(oma, syn));       \
        syn = __fadd_rn(__fmul_rn(beta, syn), __fmul_rn(omb, (xv)));       \
        spike = (__fsub_rn(mem, thr) >= 0.0f) ? 1.0f : 0.0f;               \
        __builtin_nontemporal_store(spike, &op[(size_t)(tt) * LIF_H]);     \
    } while (0)

    float bufA[LIF_U], bufB[LIF_U];
    #pragma unroll
    for (int u = 0; u < LIF_U; ++u) bufA[u] = xp[(size_t)u * LIF_H];
    #pragma unroll
    for (int u = 0; u < LIF_U; ++u) bufB[u] = xp[(size_t)(LIF_U + u) * LIF_H];

    // steady state: t = 0,40,...,920  (24 iterations). Prefetches stay
    // in-bounds: at t=920 we load x[960..999].
    for (int t = 0; t < LIF_T - 2 * LIF_U; t += 2 * LIF_U) {
        #pragma unroll
        for (int u = 0; u < LIF_U; ++u) LIF_STEP(bufA[u], t + u);
        #pragma unroll
        for (int u = 0; u < LIF_U; ++u)
            bufA[u] = xp[(size_t)(t + 2 * LIF_U + u) * LIF_H];

        #pragma unroll
        for (int u = 0; u < LIF_U; ++u) LIF_STEP(bufB[u], t + LIF_U + u);
        #pragma unroll
        for (int u = 0; u < LIF_U; ++u)
            bufB[u] = xp[(size_t)(t + 3 * LIF_U + u) * LIF_H];
    }

    // epilogue: last two chunks (t = 960..999), no more prefetch
    #pragma unroll
    for (int u = 0; u < LIF_U; ++u) LIF_STEP(bufA[u], (LIF_T - 2 * LIF_U) + u);
    #pragma unroll
    for (int u = 0; u < LIF_U; ++u) LIF_STEP(bufB[u], (LIF_T - LIF_U) + u);

#undef LIF_STEP
}

extern "C" void kernel_launch(void* const* d_in, const int* in_sizes, int n_in,
                              void* d_out, int out_size, void* d_ws, size_t ws_size,
                              hipStream_t stream) {
    const float* x     = (const float*)d_in[0];
    const float* decay = (const float*)d_in[1];
    const float* thr   = (const float*)d_in[2];
    float* out = (float*)d_out;

    const int total = LIF_B * LIF_H;           // 32768 threads
    const int block = 64;
    const int grid  = total / block;           // 512 blocks -> 2 waves/CU
    lif_kernel<<<grid, block, 0, stream>>>(x, decay, thr, out);
}

// Round 4
// 238.780 us; speedup vs baseline: 1.2218x; 1.0299x over previous
//
#include <hip/hip_runtime.h>

// LIF recurrence over T, parallel over (B,H). x,out: (B,T,H) fp32.
// B=64, T=1000, H=512.
// Thread handles TWO adjacent h (float2 loads/stores): 16384 threads =
// 256 waves, 1 wave/CU. Latency hiding is pure MLP: triple-buffered
// register pipeline at distance 2 -> 40 float2 (20KB)/wave in flight.
// __launch_bounds__(64,1) gives the scheduler a 256-VGPR budget so it
// does NOT collapse the pipeline (round-3 failure mode: VGPR capped at 36).

#define LIF_B 64
#define LIF_T 1000
#define LIF_H 512
#define LIF_U 20              // timesteps per chunk; 50 chunks total
#define LIF_W (LIF_H / 2)     // float2 elements per row = 256

typedef float f2 __attribute__((ext_vector_type(2)));

__global__ __launch_bounds__(64, 1) void lif_kernel(
    const float* __restrict__ x,
    const float* __restrict__ decay,
    const float* __restrict__ thr_p,
    float* __restrict__ out)
{
    const int n  = blockIdx.x * 64 + threadIdx.x;  // 0..16383
    const int b  = n >> 8;                         // / LIF_W
    const int hp = n & (LIF_W - 1);                // float2 index within row

    // clamp(0.5, v, 1.0)
    const float alpha = fminf(fmaxf(decay[0], 0.5f), 1.0f);
    const float beta  = fminf(fmaxf(decay[1], 0.5f), 1.0f);
    // match XLA's separate-op rounding; no fma contraction anywhere
    const float oma = __fsub_rn(1.0f, alpha);
    const float omb = __fsub_rn(1.0f, beta);
    const float thr = thr_p[0];

    const f2* xp = (const f2*)(x + (size_t)b * LIF_T * LIF_H) + hp;
    f2*       op = (f2*)(out + (size_t)b * LIF_T * LIF_H) + hp;

    float mem0 = 0.f, syn0 = 0.f, spk0 = 0.f;
    float mem1 = 0.f, syn1 = 0.f, spk1 = 0.f;

// one LIF timestep for both h's, consuming float2 v, storing at time tt
#define LIF_STEP(v, tt) do {                                               \
        const float r0_ = __fmul_rn(mem0, spk0);                           \
        mem0 = __fsub_rn(mem0, r0_);                                       \
        mem0 = __fadd_rn(__fmul_rn(alpha, mem0), __fmul_rn(oma, syn0));    \
        syn0 = __fadd_rn(__fmul_rn(beta, syn0), __fmul_rn(omb, (v).x));    \
        spk0 = (__fsub_rn(mem0, thr) >= 0.0f) ? 1.0f : 0.0f;               \
        const float r1_ = __fmul_rn(mem1, spk1);                           \
        mem1 = __fsub_rn(mem1, r1_);                                       \
        mem1 = __fadd_rn(__fmul_rn(alpha, mem1), __fmul_rn(oma, syn1));    \
        syn1 = __fadd_rn(__fmul_rn(beta, syn1), __fmul_rn(omb, (v).y));    \
        spk1 = (__fsub_rn(mem1, thr) >= 0.0f) ? 1.0f : 0.0f;               \
        f2 s_; s_.x = spk0; s_.y = spk1;                                   \
        __builtin_nontemporal_store(s_, &op[(size_t)(tt) * LIF_W]);        \
    } while (0)

    f2 B0[LIF_U], B1[LIF_U], B2[LIF_U];

    // prologue: chunks 0 and 1
    #pragma unroll
    for (int u = 0; u < LIF_U; ++u) B0[u] = xp[(size_t)(0 * LIF_U + u) * LIF_W];
    #pragma unroll
    for (int u = 0; u < LIF_U; ++u) B1[u] = xp[(size_t)(1 * LIF_U + u) * LIF_W];

    // steady state: chunks 0..47 computed, loads run 2 chunks ahead.
    // c = 0,3,...,45 (16 iterations). Loads reach chunk c+4 <= 49 (t<=999).
    for (int c = 0; c < 48; c += 3) {
        #pragma unroll
        for (int u = 0; u < LIF_U; ++u)
            B2[u] = xp[(size_t)((c + 2) * LIF_U + u) * LIF_W];
        #pragma unroll
        for (int u = 0; u < LIF_U; ++u) LIF_STEP(B0[u], c * LIF_U + u);

        #pragma unroll
        for (int u = 0; u < LIF_U; ++u)
            B0[u] = xp[(size_t)((c + 3) * LIF_U + u) * LIF_W];
        #pragma unroll
        for (int u = 0; u < LIF_U; ++u) LIF_STEP(B1[u], (c + 1) * LIF_U + u);

        #pragma unroll
        for (int u = 0; u < LIF_U; ++u)
            B1[u] = xp[(size_t)((c + 4) * LIF_U + u) * LIF_W];
        #pragma unroll
        for (int u = 0; u < LIF_U; ++u) LIF_STEP(B2[u], (c + 2) * LIF_U + u);
    }

    // epilogue: chunks 48 (in B0) and 49 (in B1)
    #pragma unroll
    for (int u = 0; u < LIF_U; ++u) LIF_STEP(B0[u], 48 * LIF_U + u);
    #pragma unroll
    for (int u = 0; u < LIF_U; ++u) LIF_STEP(B1[u], 49 * LIF_U + u);

#undef LIF_STEP
}

extern "C" void kernel_launch(void* const* d_in, const int* in_sizes, int n_in,
                              void* d_out, int out_size, void* d_ws, size_t ws_size,
                              hipStream_t stream) {
    const float* x     = (const float*)d_in[0];
    const float* decay = (const float*)d_in[1];
    const float* thr   = (const float*)d_in[2];
    float* out = (float*)d_out;

    const int total = LIF_B * LIF_H / 2;       // 16384 threads (float2 each)
    const int block = 64;
    const int grid  = total / block;           // 256 blocks -> 1 wave/CU
    lif_kernel<<<grid, block, 0, stream>>>(x, decay, thr, out);
}

// Round 9
// 236.949 us; speedup vs baseline: 1.2312x; 1.0077x over previous
//
#include <hip/hip_runtime.h>

// LIF recurrence over T, parallel over (B,H). x,out: (B,T,H) fp32.
// B=64, T=1000, H=512. 512 blocks x 64 threads = 1 wave/block, 2 waves/CU.
//
// Pipeline is pinned via LDS-DMA (global_load_lds) + hand-counted vmcnt:
// the payload never touches destination VGPRs, so the register allocator
// cannot collapse (r2-4) or corrupt (r5-7) the pipeline. Loads retire in
// order, so VWAIT(N) with N = (#loads issued after L(c)) guarantees L(c)
// landed; stores in the FIFO only make waits stricter (never unsafe).
//
// Staging trick: one width-16 global_load_lds stages 4 rows of 64 floats:
// lane i loads x[row u+(i>>4)][h0+(i&15)*4 .. +3] -> LDS byte 16*i, which
// equals row-linear layout because (l>>2)*16+(l&3)*4 == 4*l.

#define LIF_T 1000
#define LIF_H 512
#define U 40          // timesteps per chunk; 25 chunks
#define NB 4          // LDS buffers; prefetch distance 3

#define AS1 __attribute__((address_space(1)))
#define AS3 __attribute__((address_space(3)))

__global__ __launch_bounds__(64, 1) void lif_kernel(
    const float* __restrict__ x,
    const float* __restrict__ decay,
    const float* __restrict__ thr_p,
    float* __restrict__ out)
{
    __shared__ float lds[NB][U][64];   // 40960 B

    const int lane = threadIdx.x;          // 0..63
    const int blk  = blockIdx.x;           // 0..511
    const int b    = blk >> 3;             // batch
    const int h0   = (blk & 7) << 6;       // column base (multiple of 64)

    // clamp(0.5, v, 1.0)
    const float alpha = fminf(fmaxf(decay[0], 0.5f), 1.0f);
    const float beta  = fminf(fmaxf(decay[1], 0.5f), 1.0f);
    // match XLA's separate-op rounding; no fma contraction anywhere
    const float oma = __fsub_rn(1.0f, alpha);
    const float omb = __fsub_rn(1.0f, beta);
    const float thr = thr_p[0];

    // per-lane global source for staging (row lane>>4, 16B slice (lane&15))
    const float* gsrc = x + ((size_t)b * LIF_T + (lane >> 4)) * LIF_H
                          + h0 + (lane & 15) * 4;
    float* op = out + (size_t)b * LIF_T * LIF_H + h0 + lane;

    // LDS byte offset of this lane's column within buffer 0
    const unsigned lbase = (unsigned)(size_t)(const AS3 void*)&lds[0][0][0]
                         + (unsigned)lane * 4u;

    float mem = 0.f, syn = 0.f, spike = 0.f;

// stage chunk c into buffer buf: 10 width-16 LDS-DMA ops (4 rows each)
#define ISSUE(c, buf) do {                                                  \
    _Pragma("unroll")                                                       \
    for (int g = 0; g < U / 4; ++g)                                         \
        __builtin_amdgcn_global_load_lds(                                   \
            (AS1 void*)(gsrc + (size_t)((c) * U + g * 4) * LIF_H),          \
            (AS3 void*)&lds[buf][g * 4][0], 16, 0, 0);                      \
} while (0)

// counted vmcnt wait + scheduling fence (rule 18)
#define VWAIT(nn) do {                                                      \
    asm volatile("s_waitcnt vmcnt(" #nn ")" ::: "memory");                  \
    __builtin_amdgcn_sched_barrier(0); } while (0)

// consume chunk c from buffer buf: 40 ds_read -> lgkmcnt(0) -> 40 LIF steps
#define COMPUTE(c, buf) do {                                                \
    float xv[U];                                                            \
    _Pragma("unroll")                                                       \
    for (int u = 0; u < U; ++u)                                             \
        asm volatile("ds_read_b32 %0, %1" : "=v"(xv[u])                     \
            : "v"(lbase + (unsigned)(((buf) * U + u) * 256)));              \
    asm volatile("s_waitcnt lgkmcnt(0)" ::: "memory");                      \
    __builtin_amdgcn_sched_barrier(0);                                      \
    _Pragma("unroll")                                                       \
    for (int u = 0; u < U; ++u) {                                           \
        const float r_ = __fmul_rn(mem, spike);                             \
        mem = __fsub_rn(mem, r_);                                           \
        mem = __fadd_rn(__fmul_rn(alpha, mem), __fmul_rn(oma, syn));        \
        syn = __fadd_rn(__fmul_rn(beta, syn), __fmul_rn(omb, xv[u]));       \
        spike = (__fsub_rn(mem, thr) >= 0.0f) ? 1.0f : 0.0f;                \
        __builtin_nontemporal_store(spike,                                  \
            op + (size_t)((c) * U + u) * LIF_H);                            \
    }                                                                       \
} while (0)

    // prologue: fill all 4 buffers (40 LDS-DMA ops in flight)
    ISSUE(0, 0); ISSUE(1, 1); ISSUE(2, 2); ISSUE(3, 3);

    // steady state: chunk c uses buffer c&3; 30 younger loads at each wait.
    // WAR on LDS is safe: ds_reads of chunk c retire at lgkmcnt(0) before
    // ISSUE(c+4) is issued, and its writes land even later.
    #pragma unroll 1
    for (int c = 0; c <= 16; c += 4) {
        VWAIT(30); COMPUTE(c + 0, 0); ISSUE(c + 4, 0);
        VWAIT(30); COMPUTE(c + 1, 1); ISSUE(c + 5, 1);
        VWAIT(30); COMPUTE(c + 2, 2); ISSUE(c + 6, 2);
        VWAIT(30); COMPUTE(c + 3, 3); ISSUE(c + 7, 3);
    }

    // epilogue: chunks 20..24 (loads end at chunk 24)
    VWAIT(30); COMPUTE(20, 0); ISSUE(24, 0);
    VWAIT(30); COMPUTE(21, 1);   // younger loads: L22,L23,L24 = 30
    VWAIT(20); COMPUTE(22, 2);   // younger loads: L23,L24 = 20
    VWAIT(10); COMPUTE(23, 3);   // younger loads: L24 = 10
    VWAIT(0);  COMPUTE(24, 0);   // drain

#undef ISSUE
#undef VWAIT
#undef COMPUTE
}

extern "C" void kernel_launch(void* const* d_in, const int* in_sizes, int n_in,
                              void* d_out, int out_size, void* d_ws, size_t ws_size,
                              hipStream_t stream) {
    const float* x     = (const float*)d_in[0];
    const float* decay = (const float*)d_in[1];
    const float* thr   = (const float*)d_in[2];
    float* out = (float*)d_out;

    const int grid = 512;   // 64 batches x 8 column-groups
    lif_kernel<<<grid, 64, 0, stream>>>(x, decay, thr, out);
}